// Round 4
// baseline (5085.857 us; speedup 1.0000x reference)
//
#include <hip/hip_runtime.h>
#include <stdint.h>

typedef unsigned int u32;
typedef unsigned long long u64;

#define Bb 4
#define Nn 8192
#define Dd 64
#define Kk 32
#define MAXIT 30
#define NBLK 128   // 4 batches x 32 blocks; 128 threads, 2 points/thread

// ---- workspace layout (bytes); total ~6.35 MB ----
enum : u32 {
  WS_BAR   = 0u,        // 2 u32 barrier state (zeroed by kinit)
  WS_SEL   = 64u,       // 32 u32
  WS_MASKH = 192u,      // [par][4*32] u32 masks of head points
  WS_C0    = 1280u,     // 4*32*64 f
  WS_XHEAD = 34048u,    // 4*32*64 f  (mutable first-32 rows of X)
  WS_KEYS1 = 66816u,    // 8192 u32
  WS_KEYS2 = 99584u,
  WS_A1K   = 132352u,   // sorted (key,idx) round 1
  WS_A1V   = 165120u,
  WS_A2K   = 197888u,
  WS_A2V   = 230656u,
  WS_PCHG  = 263424u,   // [par][128] u32
  WS_PCNT  = 264448u,   // [par][4][32][32] u32
  WS_POBJ  = 297216u,   // [4][32] f
  WS_PMIN  = 297728u,   // [4][32 k][32 blk] u64 packed (dist,idx)
  WS_PSUM  = 330496u,   // [par][4][32][2080] f  (2048 sums d-major + 32 W)
  WS_DM    = 2460416u   // [4][32][8192] f final distances
};

// Threefry-2x32, 20 rounds — matches jax._src.prng
__device__ __forceinline__ void tf2x32(u32 k0, u32 k1, u32 x0, u32 x1, u32& o0, u32& o1){
  u32 ks2 = k0 ^ k1 ^ 0x1BD11BDAu;
  x0 += k0; x1 += k1;
#define TFR(r) { x0 += x1; x1 = (x1<<(r))|(x1>>(32-(r))); x1 ^= x0; }
  TFR(13) TFR(15) TFR(26) TFR(6)
  x0 += k1;  x1 += ks2 + 1u;
  TFR(17) TFR(29) TFR(16) TFR(24)
  x0 += ks2; x1 += k0 + 2u;
  TFR(13) TFR(15) TFR(26) TFR(6)
  x0 += k0;  x1 += k1 + 3u;
  TFR(17) TFR(29) TFR(16) TFR(24)
  x0 += k1;  x1 += ks2 + 4u;
  TFR(13) TFR(15) TFR(26) TFR(6)
  x0 += ks2; x1 += k0 + 5u;
#undef TFR
  o0 = x0; o1 = x1;
}

// ---------------- init kernel: PRNG + 2 stable sorts + C0/Xhead/barrier init ----
__global__ __launch_bounds__(1024, 1) void kinit(const float* __restrict__ E, char* __restrict__ ws){
  const int tid = threadIdx.x;
  u32* bar   = (u32*)(ws + WS_BAR);
  u32* sel   = (u32*)(ws + WS_SEL);
  u32* keys1 = (u32*)(ws + WS_KEYS1);
  u32* keys2 = (u32*)(ws + WS_KEYS2);
  u32* a1k = (u32*)(ws + WS_A1K); u32* a1v = (u32*)(ws + WS_A1V);
  u32* a2k = (u32*)(ws + WS_A2K); u32* a2v = (u32*)(ws + WS_A2V);
  float* C0 = (float*)(ws + WS_C0);
  float* XH = (float*)(ws + WS_XHEAD);

  __shared__ u32 hist[8192];
  __shared__ u32 lsum[1024];
  __shared__ u32 sel_s[32];

  if (tid < 4) bar[tid] = 0u;

  // key chain (threefry_partitionable=True semantics):
  // root=(0,42); k_init = enc_root(0,0)
  u32 i0,i1; tf2x32(0u,42u, 0u,0u, i0,i1);
  // round1: key1 = enc_kinit(0,0); sub1 = enc_kinit(0,1)
  u32 key10,key11, s10,s11;
  tf2x32(i0,i1, 0u,0u, key10,key11);
  tf2x32(i0,i1, 0u,1u, s10,s11);
  // round2: sub2 = enc_key1(0,1)
  u32 s20,s21; tf2x32(key10,key11, 0u,1u, s20,s21);

  // sort keys: bits32 = y0 ^ y1 of enc_sub(0, i)   (partitionable random_bits)
  for (int i = tid; i < 8192; i += 1024){
    u32 y0,y1;
    tf2x32(s10,s11, 0u,(u32)i, y0,y1); keys1[i] = y0 ^ y1;
    tf2x32(s20,s21, 0u,(u32)i, y0,y1); keys2[i] = y0 ^ y1;
  }
  // Xhead = first 32 rows of each batch
  for (int i = tid; i < 8192; i += 1024){
    int b = i >> 11; int rem = i & 2047;
    XH[i] = E[(size_t)b*Nn*Dd + rem];
  }
  __syncthreads();

  // two stable sorts: bucket by top 13 bits, insertion-sort buckets by (key, idx)
  for (int rnd = 0; rnd < 2; rnd++){
    u32* keys = rnd ? keys2 : keys1;
    u32* ak   = rnd ? a2k   : a1k;
    u32* av   = rnd ? a2v   : a1v;
    for (int i = tid; i < 8192; i += 1024) hist[i] = 0u;
    __syncthreads();
    for (int i = tid; i < 8192; i += 1024) atomicAdd(&hist[keys[i]>>19], 1u);
    __syncthreads();
    // exclusive scan of 8192 buckets
    { u32 s = 0;
      for (int j = 0; j < 8; j++) s += hist[tid*8+j];
      lsum[tid] = s; }
    __syncthreads();
    for (int st = 1; st < 1024; st <<= 1){
      u32 v = (tid >= st) ? lsum[tid-st] : 0u;
      __syncthreads();
      lsum[tid] += v;
      __syncthreads();
    }
    { u32 run = tid ? lsum[tid-1] : 0u;
      for (int j = 0; j < 8; j++){ u32 c = hist[tid*8+j]; hist[tid*8+j] = run; run += c; } }
    __syncthreads();
    // scatter (hist becomes end-offsets)
    for (int i = tid; i < 8192; i += 1024){
      u32 kx = keys[i];
      u32 pos = atomicAdd(&hist[kx>>19], 1u);
      ak[pos] = kx; av[pos] = (u32)i;
    }
    __syncthreads();
    // per-bucket insertion sort -> total order == stable sort by key
    for (int bkt = tid; bkt < 8192; bkt += 1024){
      int s0 = bkt ? (int)hist[bkt-1] : 0;
      int e0 = (int)hist[bkt];
      for (int i = s0+1; i < e0; i++){
        u32 kx = ak[i], vx = av[i];
        int j = i-1;
        while (j >= s0 && (ak[j] > kx || (ak[j] == kx && av[j] > vx))){
          ak[j+1] = ak[j]; av[j+1] = av[j]; j--;
        }
        ak[j+1] = kx; av[j+1] = vx;
      }
    }
    __syncthreads();
  }
  // sel[j] = perm2[j] = perm1[pos of j-th smallest keys2]
  if (tid < 32){ u32 p = a2v[tid]; u32 sj = a1v[p]; sel[tid] = sj; sel_s[tid] = sj; }
  __syncthreads();
  // C0[b][k][d] = E[b][sel[k]][d]
  for (int i = tid; i < 8192; i += 1024){
    int b = i >> 11; int k = (i >> 6) & 31; int d = i & 63;
    C0[i] = E[(size_t)b*Nn*Dd + (size_t)sel_s[k]*Dd + d];
  }
}

// device-scope sense-reversing grid barrier (128 co-resident blocks)
// Fence-minimal protocol: RELEASE arrival RMW, RELAXED spin (ACQUIRE hedge every
// 64 polls), single ACQUIRE agent fence on wake.
__device__ __forceinline__ void grid_barrier(u32* bar){
  __syncthreads();
  if (threadIdx.x == 0){
    u32 g = __hip_atomic_load(&bar[1], __ATOMIC_RELAXED, __HIP_MEMORY_SCOPE_AGENT);
    u32 a = __hip_atomic_fetch_add(&bar[0], 1u, __ATOMIC_RELEASE, __HIP_MEMORY_SCOPE_AGENT);
    if (a == (u32)(NBLK-1)){
      __hip_atomic_store(&bar[0], 0u, __ATOMIC_RELAXED, __HIP_MEMORY_SCOPE_AGENT);
      __hip_atomic_store(&bar[1], g + 1u, __ATOMIC_RELEASE, __HIP_MEMORY_SCOPE_AGENT);
    } else {
      int polls = 0;
      for (;;){
        u32 v = __hip_atomic_load(&bar[1], __ATOMIC_RELAXED, __HIP_MEMORY_SCOPE_AGENT);
        if (v != g) break;
        if ((++polls & 63) == 0){
          v = __hip_atomic_load(&bar[1], __ATOMIC_ACQUIRE, __HIP_MEMORY_SCOPE_AGENT);
          if (v != g) break;
        }
        __builtin_amdgcn_s_sleep(2);
      }
    }
    __builtin_amdgcn_fence(__ATOMIC_ACQUIRE, "agent");
  }
  __syncthreads();
}

#define CALC_XX(xv, xxv) do { float s0=0.f,s1=0.f,s2=0.f,s3=0.f; \
  _Pragma("unroll") \
  for (int j=0;j<16;j++){ s0+=xv[4*j]*xv[4*j]; s1+=xv[4*j+1]*xv[4*j+1]; s2+=xv[4*j+2]*xv[4*j+2]; s3+=xv[4*j+3]*xv[4*j+3]; } \
  xxv=(s0+s1)+(s2+s3); } while(0)

// fused dist for both points: each C float4 is read from LDS ONCE and feeds
// both points' FMA chains (halves per-CU LDS-pipe traffic vs 1 pt/thread)
#define CALC_DIST2() do { \
  _Pragma("unroll") \
  for (int k=0;k<32;k++){ \
    const float4* cp = (const float4*)&Cl[k*64]; \
    float s0=0.f,s1=0.f,s2=0.f,s3=0.f; \
    float t0=0.f,t1=0.f,t2=0.f,t3=0.f; \
    _Pragma("unroll") \
    for (int j=0;j<16;j++){ float4 c = cp[j]; \
      s0+=x0[4*j]*c.x; s1+=x0[4*j+1]*c.y; s2+=x0[4*j+2]*c.z; s3+=x0[4*j+3]*c.w; \
      t0+=x1[4*j]*c.x; t1+=x1[4*j+1]*c.y; t2+=x1[4*j+2]*c.z; t3+=x1[4*j+3]*c.w; } \
    float dot0=(s0+s1)+(s2+s3); \
    float dot1=(t0+t1)+(t2+t3); \
    dloc0[k]=(ccl[k]+xx0)-2.f*dot0; \
    dloc1[k]=(ccl[k]+xx1)-2.f*dot1; \
  } } while(0)

__global__ __launch_bounds__(128, 1) void kmain(const float* __restrict__ E, const float* __restrict__ LW,
                                                float* __restrict__ out, char* __restrict__ ws){
  const int tid = threadIdx.x;
  const int bid = blockIdx.x;
  const int b   = bid >> 5;
  const int blk = bid & 31;
  const int n0  = (blk << 8) + tid;        // point 0 (tids 0..31 of blk 0 own head rows)
  const int n1  = n0 + 128;                // point 1

  u32*   bar   = (u32*)(ws + WS_BAR);
  u32*   maskh = (u32*)(ws + WS_MASKH);
  float* C0    = (float*)(ws + WS_C0);
  float* XH    = (float*)(ws + WS_XHEAD);
  u32*   Pchg  = (u32*)(ws + WS_PCHG);
  u32*   Pcnt  = (u32*)(ws + WS_PCNT);
  float* Pobj  = (float*)(ws + WS_POBJ);
  u64*   Pmin  = (u64*)(ws + WS_PMIN);
  float* Psum  = (float*)(ws + WS_PSUM);
  float* Dm    = (float*)(ws + WS_DM);

  __shared__ float Cl[2048];      // C[k][d] (k-major, float4 broadcast reads)
  __shared__ float ccl[32];
  __shared__ float part[2080];    // sums d-major: part[d*32+k]; W at part[2048+k]
  __shared__ u32   cntl[32];
  __shared__ u32   cntall[128];   // reduced counts, all batches
  __shared__ u32   chg_s[128];
  __shared__ float newX[2048];    // replacement rows staging / rep accumulator
  __shared__ u64   kminl[32];
  __shared__ float red[128];
  __shared__ u32   sh_chg, sh_empty, sh_idx, sh_tcnt;
  __shared__ float sh_mind;

  // load this thread's two points into registers
  float x0[64], x1[64]; float xx0, xx1;
  { const float4* xr0 = (const float4*)(E + (size_t)(b*Nn + n0)*Dd);
    const float4* xr1 = (const float4*)(E + (size_t)(b*Nn + n1)*Dd);
    #pragma unroll
    for (int j=0;j<16;j++){ float4 v = xr0[j]; x0[4*j]=v.x; x0[4*j+1]=v.y; x0[4*j+2]=v.z; x0[4*j+3]=v.w; }
    #pragma unroll
    for (int j=0;j<16;j++){ float4 v = xr1[j]; x1[4*j]=v.x; x1[4*j+1]=v.y; x1[4*j+2]=v.z; x1[4*j+3]=v.w; } }
  CALC_XX(x0, xx0);
  CALC_XX(x1, xx1);
  const float w0 = expf(LW[b*Nn + n0]);  // weight is positional, constant
  const float w1 = expf(LW[b*Nn + n1]);

  // k_loop = enc_(0,42)(0,1)  (for empty-cluster randint path)
  u32 kl0, kl1; tf2x32(0u,42u, 0u,1u, kl0, kl1);

  for (int i = tid; i < 2048; i += 128) Cl[i] = C0[b*2048 + i];
  __syncthreads();
  if (tid < 32){ float s=0.f; const float* cr=&Cl[tid*64];
    #pragma unroll
    for (int d2=0; d2<64; d2++) s += cr[d2]*cr[d2];
    ccl[tid]=s; }
  __syncthreads();

  u32 prevmask0 = 0u, prevmask1 = 0u;
  float dloc0[32], dloc1[32];

  for (int t = 0; t < MAXIT; t++){
    const int par = t & 1;
    // ---------- phase 1: assignment + per-block partial sums ----------
    CALC_DIST2();
    float mind0 = dloc0[0], mind1 = dloc1[0];
    #pragma unroll
    for (int k=1;k<32;k++){ mind0 = fminf(mind0, dloc0[k]); mind1 = fminf(mind1, dloc1[k]); }
    u32 mask0 = 0u, mask1 = 0u;
    #pragma unroll
    for (int k=0;k<32;k++){
      if (fabsf(dloc0[k]-mind0) < 1e-8f) mask0 |= (1u<<k);
      if (fabsf(dloc1[k]-mind1) < 1e-8f) mask1 |= (1u<<k);
    }
    int changed = (t==0) ? 1 : ((mask0 != prevmask0) || (mask1 != prevmask1));
    prevmask0 = mask0; prevmask1 = mask1;
    if (blk == 0 && tid < 32) maskh[par*128 + b*32 + tid] = mask0;

    __syncthreads();
    for (int i = tid; i < 2080; i += 128) part[i] = 0.f;
    if (tid < 32) cntl[tid] = 0u;
    __syncthreads();
    { u32 mm = mask0;
      while (mm){
        int k = __ffs(mm) - 1; mm &= mm - 1;
        #pragma unroll
        for (int d2=0; d2<64; d2++) atomicAdd(&part[d2*32 + k], w0*x0[d2]);
        atomicAdd(&part[2048 + k], w0);
        atomicAdd(&cntl[k], 1u);
      } }
    { u32 mm = mask1;
      while (mm){
        int k = __ffs(mm) - 1; mm &= mm - 1;
        #pragma unroll
        for (int d2=0; d2<64; d2++) atomicAdd(&part[d2*32 + k], w1*x1[d2]);
        atomicAdd(&part[2048 + k], w1);
        atomicAdd(&cntl[k], 1u);
      } }
    int nchg = __syncthreads_count(changed);
    { float* dst = Psum + (size_t)(((par*4)+b)*32 + blk) * 2080;
      for (int i = tid; i < 2080; i += 128) dst[i] = part[i];
      if (tid < 32) Pcnt[(((par*4)+b)*32 + blk)*32 + tid] = cntl[tid];
      if (tid == 0) Pchg[par*128 + bid] = (u32)nchg; }
    grid_barrier(bar);

    // ---------- phase 2: every block reduces -> its own C in LDS ----------
    if (tid < 128){
      u32 s = 0; int bb = tid >> 5, kq = tid & 31;
      for (int bl = 0; bl < 32; bl++) s += Pcnt[(((par*4)+bb)*32 + bl)*32 + kq];
      cntall[tid] = s;
      chg_s[tid] = Pchg[par*128 + tid];
    }
    __syncthreads();
    if (tid == 0){
      u32 c = 0, ae = 0;
      for (int i2 = 0; i2 < 128; i2++){ c += chg_s[i2]; ae |= (cntall[i2] == 0u) ? 1u : 0u; }
      sh_chg = c; sh_empty = ae;
    }
    __syncthreads();
    if (sh_chg == 0u) break;   // global convergence: state frozen (matches reference)

    { const float* src = Psum + (size_t)(((par*4)+b)*32) * 2080;
      for (int i = tid; i < 2080; i += 128){
        float s = 0.f;
        for (int bl = 0; bl < 32; bl++) s += src[bl*2080 + i];
        part[i] = s;
      } }
    __syncthreads();

    if (sh_empty){
      // empty-cluster replacement: X rows j (=cluster idx) replaced BEFORE C update,
      // weights/assignments from pre-replacement X. All blocks apply identical fixup.
      u32 g0, g1; tf2x32(kl0, kl1, 0u, (u32)t, g0, g1);   // fold_in(k_loop, t)
      for (int k = 0; k < 32; k++){
        if (cntall[b*32 + k] != 0u) continue;
        int j = b*32 + k;
        u32 y0, y1; tf2x32(g0, g1, 0u, (u32)j, y0, y1);   // partitionable bits: y0^y1
        u32 ridx = (y0 ^ y1) & 8191u;
        u32 mj = maskh[par*128 + b*32 + k];
        float wj = expf(LW[b*Nn + k]);
        if (tid < 64){
          float xo = XH[(b*32 + k)*64 + tid];
          float xn = (ridx < 32u) ? XH[(b*32 + (int)ridx)*64 + tid]
                                  : E[(size_t)(b*Nn + (int)ridx)*Dd + tid];
          newX[k*64 + tid] = xn;
          float dxw = wj * (xn - xo);
          u32 m2 = mj;
          while (m2){ int kq = __ffs(m2) - 1; m2 &= m2 - 1; part[tid*32 + kq] += dxw; }
        }
      }
      __syncthreads();
      grid_barrier(bar);      // all fixup reads of old Xhead complete before writes
      if (blk == 0){
        for (int k = 0; k < 32; k++){
          if (cntall[b*32 + k] != 0u) continue;
          if (tid < 64) XH[(b*32 + k)*64 + tid] = newX[k*64 + tid];
        }
        __syncthreads();
        if (tid < 32 && cntall[b*32 + tid] == 0u){
          #pragma unroll
          for (int d2 = 0; d2 < 64; d2++) x0[d2] = newX[tid*64 + d2];
          CALC_XX(x0, xx0);
        }
      }
    }
    __syncthreads();
    // C_new = sums / clip(W, 1e-12)  (empty -> 0, matching reference)
    for (int i = tid; i < 2048; i += 128){
      int k = i >> 6, d = i & 63;
      Cl[i] = part[d*32 + k] / fmaxf(part[2048 + k], 1e-12f);
    }
    __syncthreads();
    if (tid < 32){ float s=0.f; const float* cr=&Cl[tid*64];
      #pragma unroll
      for (int d2=0; d2<64; d2++) s += cr[d2]*cr[d2];
      ccl[tid]=s; }
    __syncthreads();
  }

  // ---------- finalize 1: Dm with final C; ass from LAST assignment; partial mins/obj ----------
  CALC_DIST2();
  float mind0 = dloc0[0], mind1 = dloc1[0];
  #pragma unroll
  for (int k=1;k<32;k++){ mind0 = fminf(mind0, dloc0[k]); mind1 = fminf(mind1, dloc1[k]); }
  #pragma unroll
  for (int k=0;k<32;k++){
    Dm[(size_t)(b*32 + k)*Nn + n0] = dloc0[k];
    Dm[(size_t)(b*32 + k)*Nn + n1] = dloc1[k];
  }
  { float4* dst0 = (float4*)(out + (size_t)(b*Nn + n0)*32);
    float4* dst1 = (float4*)(out + (size_t)(b*Nn + n1)*32);
    #pragma unroll
    for (int q=0;q<8;q++){
      float4 v;
      v.x = ((prevmask0>>(4*q  ))&1u) ? 1.f : 0.f;
      v.y = ((prevmask0>>(4*q+1))&1u) ? 1.f : 0.f;
      v.z = ((prevmask0>>(4*q+2))&1u) ? 1.f : 0.f;
      v.w = ((prevmask0>>(4*q+3))&1u) ? 1.f : 0.f;
      dst0[q] = v;
      v.x = ((prevmask1>>(4*q  ))&1u) ? 1.f : 0.f;
      v.y = ((prevmask1>>(4*q+1))&1u) ? 1.f : 0.f;
      v.z = ((prevmask1>>(4*q+2))&1u) ? 1.f : 0.f;
      v.w = ((prevmask1>>(4*q+3))&1u) ? 1.f : 0.f;
      dst1[q] = v;
    } }
  if (tid < 32) kminl[tid] = ~0ull;
  red[tid] = mind0 + mind1;
  __syncthreads();
  #pragma unroll
  for (int k=0;k<32;k++){
    u32 u = __float_as_uint(dloc0[k]);
    u = (u & 0x80000000u) ? ~u : (u | 0x80000000u);  // monotone encode (handles negatives)
    u64 pk = ((u64)u << 32) | (u32)n0;               // tie -> smaller n (first argmin)
    atomicMin(&kminl[k], pk);
    u32 u2 = __float_as_uint(dloc1[k]);
    u2 = (u2 & 0x80000000u) ? ~u2 : (u2 | 0x80000000u);
    u64 pk2 = ((u64)u2 << 32) | (u32)n1;
    atomicMin(&kminl[k], pk2);
  }
  for (int s2 = 64; s2 > 0; s2 >>= 1){
    if (tid < s2) red[tid] += red[tid + s2];
    __syncthreads();
  }
  if (tid < 32) Pmin[(size_t)(b*32 + tid)*32 + blk] = kminl[tid];
  if (tid == 0) Pobj[b*32 + blk] = red[0];
  grid_barrier(bar);

  // ---------- finalize 2: block -> (b2,k2): rep_idx, rep, C, obj ----------
  {
    const int b2 = bid >> 5, k2 = bid & 31;
    const size_t OFF_C    = (size_t)Bb*Nn*Kk;        // 1048576
    const size_t OFF_REP  = OFF_C + (size_t)Bb*Kk*Dd;
    const size_t OFF_RIDX = OFF_REP + (size_t)Bb*Kk*Dd;
    const size_t OFF_OBJ  = OFF_RIDX + (size_t)Bb*Kk;
    if (tid == 0){
      u64 m = ~0ull;
      for (int bl = 0; bl < 32; bl++){ u64 v = Pmin[(size_t)(b2*32 + k2)*32 + bl]; if (v < m) m = v; }
      u32 enc = (u32)(m >> 32);
      u32 ub  = (enc & 0x80000000u) ? (enc & 0x7fffffffu) : ~enc;
      sh_mind = __uint_as_float(ub);
      sh_idx  = (u32)(m & 0xffffffffu);
      sh_tcnt = 0u;
    }
    if (tid < 64) newX[tid] = 0.f;   // rep accumulator
    __syncthreads();
    float mr = sh_mind;
    for (int nn = tid; nn < Nn; nn += 128){
      float dv = Dm[(size_t)(b2*32 + k2)*Nn + nn];
      if (fabsf(dv - mr) < 1e-8f){
        atomicAdd(&sh_tcnt, 1u);
        const float* xr = (nn < 32) ? &XH[(b2*32 + nn)*64] : &E[(size_t)(b2*Nn + nn)*Dd];
        for (int d2 = 0; d2 < 64; d2++) atomicAdd(&newX[d2], xr[d2]);
      }
    }
    __syncthreads();
    if (tid < 64){
      out[OFF_C   + (size_t)(b2*32 + k2)*64 + tid] = Cl[k2*64 + tid];
      out[OFF_REP + (size_t)(b2*32 + k2)*64 + tid] = newX[tid] / (float)sh_tcnt;
    }
    if (tid == 0) out[OFF_RIDX + b2*32 + k2] = (float)sh_idx;
    if (k2 == 0){
      if (tid < 32) red[tid] = Pobj[b2*32 + tid];
      __syncthreads();
      if (tid == 0){ float s = 0.f; for (int i2 = 0; i2 < 32; i2++) s += red[i2];
        out[OFF_OBJ + b2] = s / (float)Nn; }
    }
  }
}

extern "C" void kernel_launch(void* const* d_in, const int* in_sizes, int n_in,
                              void* d_out, int out_size, void* d_ws, size_t ws_size,
                              hipStream_t stream) {
  const float* E  = (const float*)d_in[0];
  const float* LW = (const float*)d_in[1];
  float* out = (float*)d_out;
  char*  ws  = (char*)d_ws;
  (void)in_sizes; (void)n_in; (void)out_size; (void)ws_size;
  kinit<<<dim3(1),    dim3(1024), 0, stream>>>(E, ws);
  kmain<<<dim3(NBLK), dim3(128),  0, stream>>>(E, LW, out, ws);
}

// Round 5
// 2299.267 us; speedup vs baseline: 2.2119x; 2.2119x over previous
//
#include <hip/hip_runtime.h>
#include <stdint.h>

typedef unsigned int u32;
typedef unsigned long long u64;

#define Bb 4
#define Nn 8192
#define Dd 64
#define Kk 32
#define MAXIT 30
#define NBLK 128   // 4 batches x 32 blocks, 256 threads = 1 point/thread

// ---- workspace layout (bytes); total ~6.35 MB ----
enum : u32 {
  WS_BAR   = 0u,        // 2 u32 barrier state (zeroed by kinit)
  WS_SEL   = 64u,       // 32 u32
  WS_MASKH = 192u,      // [par][4*32] u32 masks of head points
  WS_C0    = 1280u,     // 4*32*64 f
  WS_XHEAD = 34048u,    // 4*32*64 f  (mutable first-32 rows of X)
  WS_KEYS1 = 66816u,    // 8192 u32
  WS_KEYS2 = 99584u,
  WS_A1K   = 132352u,   // sorted (key,idx) round 1
  WS_A1V   = 165120u,
  WS_A2K   = 197888u,
  WS_A2V   = 230656u,
  WS_PCHG  = 263424u,   // [par][128] u32
  WS_PCNT  = 264448u,   // [par][4][32][32] u32
  WS_POBJ  = 297216u,   // [4][32] f
  WS_PMIN  = 297728u,   // [4][32 k][32 blk] u64 packed (dist,idx)
  WS_PSUM  = 330496u,   // [par][4][32][2080] f  (2048 sums d-major + 32 W)
  WS_DM    = 2460416u   // [4][32][8192] f final distances
};

// Threefry-2x32, 20 rounds — matches jax._src.prng
__device__ __forceinline__ void tf2x32(u32 k0, u32 k1, u32 x0, u32 x1, u32& o0, u32& o1){
  u32 ks2 = k0 ^ k1 ^ 0x1BD11BDAu;
  x0 += k0; x1 += k1;
#define TFR(r) { x0 += x1; x1 = (x1<<(r))|(x1>>(32-(r))); x1 ^= x0; }
  TFR(13) TFR(15) TFR(26) TFR(6)
  x0 += k1;  x1 += ks2 + 1u;
  TFR(17) TFR(29) TFR(16) TFR(24)
  x0 += ks2; x1 += k0 + 2u;
  TFR(13) TFR(15) TFR(26) TFR(6)
  x0 += k0;  x1 += k1 + 3u;
  TFR(17) TFR(29) TFR(16) TFR(24)
  x0 += k1;  x1 += ks2 + 4u;
  TFR(13) TFR(15) TFR(26) TFR(6)
  x0 += ks2; x1 += k0 + 5u;
#undef TFR
  o0 = x0; o1 = x1;
}

// ---------------- init kernel: PRNG + 2 stable sorts + C0/Xhead/barrier init ----
__global__ __launch_bounds__(1024, 1) void kinit(const float* __restrict__ E, char* __restrict__ ws){
  const int tid = threadIdx.x;
  u32* bar   = (u32*)(ws + WS_BAR);
  u32* sel   = (u32*)(ws + WS_SEL);
  u32* keys1 = (u32*)(ws + WS_KEYS1);
  u32* keys2 = (u32*)(ws + WS_KEYS2);
  u32* a1k = (u32*)(ws + WS_A1K); u32* a1v = (u32*)(ws + WS_A1V);
  u32* a2k = (u32*)(ws + WS_A2K); u32* a2v = (u32*)(ws + WS_A2V);
  float* C0 = (float*)(ws + WS_C0);
  float* XH = (float*)(ws + WS_XHEAD);

  __shared__ u32 hist[8192];
  __shared__ u32 lsum[1024];
  __shared__ u32 sel_s[32];

  if (tid < 4) bar[tid] = 0u;

  // key chain (threefry_partitionable=True semantics):
  // root=(0,42); k_init = enc_root(0,0)
  u32 i0,i1; tf2x32(0u,42u, 0u,0u, i0,i1);
  // round1: key1 = enc_kinit(0,0); sub1 = enc_kinit(0,1)
  u32 key10,key11, s10,s11;
  tf2x32(i0,i1, 0u,0u, key10,key11);
  tf2x32(i0,i1, 0u,1u, s10,s11);
  // round2: sub2 = enc_key1(0,1)
  u32 s20,s21; tf2x32(key10,key11, 0u,1u, s20,s21);

  // sort keys: bits32 = y0 ^ y1 of enc_sub(0, i)   (partitionable random_bits)
  for (int i = tid; i < 8192; i += 1024){
    u32 y0,y1;
    tf2x32(s10,s11, 0u,(u32)i, y0,y1); keys1[i] = y0 ^ y1;
    tf2x32(s20,s21, 0u,(u32)i, y0,y1); keys2[i] = y0 ^ y1;
  }
  // Xhead = first 32 rows of each batch
  for (int i = tid; i < 8192; i += 1024){
    int b = i >> 11; int rem = i & 2047;
    XH[i] = E[(size_t)b*Nn*Dd + rem];
  }
  __syncthreads();

  // two stable sorts: bucket by top 13 bits, insertion-sort buckets by (key, idx)
  for (int rnd = 0; rnd < 2; rnd++){
    u32* keys = rnd ? keys2 : keys1;
    u32* ak   = rnd ? a2k   : a1k;
    u32* av   = rnd ? a2v   : a1v;
    for (int i = tid; i < 8192; i += 1024) hist[i] = 0u;
    __syncthreads();
    for (int i = tid; i < 8192; i += 1024) atomicAdd(&hist[keys[i]>>19], 1u);
    __syncthreads();
    // exclusive scan of 8192 buckets
    { u32 s = 0;
      for (int j = 0; j < 8; j++) s += hist[tid*8+j];
      lsum[tid] = s; }
    __syncthreads();
    for (int st = 1; st < 1024; st <<= 1){
      u32 v = (tid >= st) ? lsum[tid-st] : 0u;
      __syncthreads();
      lsum[tid] += v;
      __syncthreads();
    }
    { u32 run = tid ? lsum[tid-1] : 0u;
      for (int j = 0; j < 8; j++){ u32 c = hist[tid*8+j]; hist[tid*8+j] = run; run += c; } }
    __syncthreads();
    // scatter (hist becomes end-offsets)
    for (int i = tid; i < 8192; i += 1024){
      u32 kx = keys[i];
      u32 pos = atomicAdd(&hist[kx>>19], 1u);
      ak[pos] = kx; av[pos] = (u32)i;
    }
    __syncthreads();
    // per-bucket insertion sort -> total order == stable sort by key
    for (int bkt = tid; bkt < 8192; bkt += 1024){
      int s0 = bkt ? (int)hist[bkt-1] : 0;
      int e0 = (int)hist[bkt];
      for (int i = s0+1; i < e0; i++){
        u32 kx = ak[i], vx = av[i];
        int j = i-1;
        while (j >= s0 && (ak[j] > kx || (ak[j] == kx && av[j] > vx))){
          ak[j+1] = ak[j]; av[j+1] = av[j]; j--;
        }
        ak[j+1] = kx; av[j+1] = vx;
      }
    }
    __syncthreads();
  }
  // sel[j] = perm2[j] = perm1[pos of j-th smallest keys2]
  if (tid < 32){ u32 p = a2v[tid]; u32 sj = a1v[p]; sel[tid] = sj; sel_s[tid] = sj; }
  __syncthreads();
  // C0[b][k][d] = E[b][sel[k]][d]
  for (int i = tid; i < 8192; i += 1024){
    int b = i >> 11; int k = (i >> 6) & 31; int d = i & 63;
    C0[i] = E[(size_t)b*Nn*Dd + (size_t)sel_s[k]*Dd + d];
  }
}

// device-scope sense-reversing grid barrier (128 co-resident blocks)
// Fence-minimal protocol: RELEASE arrival RMW, RELAXED spin (ACQUIRE hedge every
// 64 polls), single ACQUIRE agent fence on wake.
__device__ __forceinline__ void grid_barrier(u32* bar){
  __syncthreads();
  if (threadIdx.x == 0){
    u32 g = __hip_atomic_load(&bar[1], __ATOMIC_RELAXED, __HIP_MEMORY_SCOPE_AGENT);
    u32 a = __hip_atomic_fetch_add(&bar[0], 1u, __ATOMIC_RELEASE, __HIP_MEMORY_SCOPE_AGENT);
    if (a == (u32)(NBLK-1)){
      __hip_atomic_store(&bar[0], 0u, __ATOMIC_RELAXED, __HIP_MEMORY_SCOPE_AGENT);
      __hip_atomic_store(&bar[1], g + 1u, __ATOMIC_RELEASE, __HIP_MEMORY_SCOPE_AGENT);
    } else {
      int polls = 0;
      for (;;){
        u32 v = __hip_atomic_load(&bar[1], __ATOMIC_RELAXED, __HIP_MEMORY_SCOPE_AGENT);
        if (v != g) break;
        if ((++polls & 63) == 0){
          v = __hip_atomic_load(&bar[1], __ATOMIC_ACQUIRE, __HIP_MEMORY_SCOPE_AGENT);
          if (v != g) break;
        }
        __builtin_amdgcn_s_sleep(2);
      }
    }
    __builtin_amdgcn_fence(__ATOMIC_ACQUIRE, "agent");
  }
  __syncthreads();
}

#define CALC_XX() do { float s0=0.f,s1=0.f,s2=0.f,s3=0.f; \
  _Pragma("unroll") \
  for (int j=0;j<16;j++){ s0+=x[4*j]*x[4*j]; s1+=x[4*j+1]*x[4*j+1]; s2+=x[4*j+2]*x[4*j+2]; s3+=x[4*j+3]*x[4*j+3]; } \
  xx=(s0+s1)+(s2+s3); } while(0)

#define CALC_DIST() do { \
  _Pragma("unroll") \
  for (int k=0;k<32;k++){ \
    const float4* cp = (const float4*)&Cl[k*64]; \
    float s0=0.f,s1=0.f,s2=0.f,s3=0.f; \
    _Pragma("unroll") \
    for (int j=0;j<16;j++){ float4 c = cp[j]; s0+=x[4*j]*c.x; s1+=x[4*j+1]*c.y; s2+=x[4*j+2]*c.z; s3+=x[4*j+3]*c.w; } \
    float dot=(s0+s1)+(s2+s3); \
    dloc[k]=(ccl[k]+xx)-2.f*dot; \
  } } while(0)

__global__ __launch_bounds__(256, 1) void kmain(const float* __restrict__ E, const float* __restrict__ LW,
                                                float* __restrict__ out, char* __restrict__ ws){
  const int tid = threadIdx.x;
  const int bid = blockIdx.x;
  const int b   = bid >> 5;
  const int blk = bid & 31;
  const int n   = (blk << 8) + tid;

  u32*   bar   = (u32*)(ws + WS_BAR);
  u32*   maskh = (u32*)(ws + WS_MASKH);
  float* C0    = (float*)(ws + WS_C0);
  float* XH    = (float*)(ws + WS_XHEAD);
  u32*   Pchg  = (u32*)(ws + WS_PCHG);
  u32*   Pcnt  = (u32*)(ws + WS_PCNT);
  float* Pobj  = (float*)(ws + WS_POBJ);
  u64*   Pmin  = (u64*)(ws + WS_PMIN);
  float* Psum  = (float*)(ws + WS_PSUM);
  float* Dm    = (float*)(ws + WS_DM);

  __shared__ float Cl[2048];      // C[k][d] (k-major, float4 broadcast reads)
  __shared__ float ccl[32];
  __shared__ __align__(16) float part[2080];    // sums d-major: part[d*32+k]; W at part[2048+k]
  __shared__ u32   cntl[32];
  __shared__ u32   cntall[128];   // reduced counts, all batches
  __shared__ u32   chg_s[128];
  __shared__ float newX[2048];    // replacement rows staging / rep accumulator
  __shared__ u64   kminl[32];
  __shared__ float red[256];
  __shared__ u32   sh_chg, sh_empty, sh_idx, sh_tcnt;
  __shared__ float sh_mind;

  // load this thread's point into registers
  float x[64]; float xx;
  { const float4* xr = (const float4*)(E + (size_t)(b*Nn + n)*Dd);
    #pragma unroll
    for (int j=0;j<16;j++){ float4 v = xr[j]; x[4*j]=v.x; x[4*j+1]=v.y; x[4*j+2]=v.z; x[4*j+3]=v.w; } }
  CALC_XX();
  const float w = expf(LW[b*Nn + n]);  // weight is positional, constant

  // k_loop = enc_(0,42)(0,1)  (for empty-cluster randint path)
  u32 kl0, kl1; tf2x32(0u,42u, 0u,1u, kl0, kl1);

  for (int i = tid; i < 2048; i += 256) Cl[i] = C0[b*2048 + i];
  __syncthreads();
  if (tid < 32){ float s=0.f; const float* cr=&Cl[tid*64];
    #pragma unroll
    for (int d2=0; d2<64; d2++) s += cr[d2]*cr[d2];
    ccl[tid]=s; }
  __syncthreads();

  u32 prevmask = 0u;
  float dloc[32];

  for (int t = 0; t < MAXIT; t++){
    const int par = t & 1;
    // ---------- phase 1: assignment + per-block partial sums ----------
    CALC_DIST();
    float mind = dloc[0];
    #pragma unroll
    for (int k=1;k<32;k++) mind = fminf(mind, dloc[k]);
    u32 mask = 0u;
    #pragma unroll
    for (int k=0;k<32;k++) if (fabsf(dloc[k]-mind) < 1e-8f) mask |= (1u<<k);
    int changed = (t==0) ? 1 : (mask != prevmask);
    prevmask = mask;
    if (blk == 0 && tid < 32) maskh[par*128 + b*32 + tid] = mask;

    __syncthreads();
    for (int i = tid; i < 2080; i += 256) part[i] = 0.f;
    if (tid < 32) cntl[tid] = 0u;
    __syncthreads();
    { u32 mm = mask;
      while (mm){
        int k = __ffs(mm) - 1; mm &= mm - 1;
        #pragma unroll
        for (int d2=0; d2<64; d2++) atomicAdd(&part[d2*32 + k], w*x[d2]);
        atomicAdd(&part[2048 + k], w);
        atomicAdd(&cntl[k], 1u);
      } }
    int nchg = __syncthreads_count(changed);
    { float4* dst = (float4*)(Psum + (size_t)(((par*4)+b)*32 + blk) * 2080);
      const float4* p4 = (const float4*)part;
      for (int i = tid; i < 520; i += 256) dst[i] = p4[i];
      if (tid < 32) Pcnt[(((par*4)+b)*32 + blk)*32 + tid] = cntl[tid];
      if (tid == 0) Pchg[par*128 + bid] = (u32)nchg; }
    grid_barrier(bar);

    // ---------- phase 2: every block reduces -> its own C in LDS ----------
    if (tid < 128){
      u32 s = 0; int bb = tid >> 5, kq = tid & 31;
      for (int bl = 0; bl < 32; bl++) s += Pcnt[(((par*4)+bb)*32 + bl)*32 + kq];
      cntall[tid] = s;
      chg_s[tid] = Pchg[par*128 + tid];
    }
    __syncthreads();
    // parallel chg-sum + empty-OR over 128 entries (wave 0 tree, replaces tid0 serial loop)
    if (tid < 64){
      u32 c = chg_s[tid] + chg_s[tid + 64];
      u32 e = ((cntall[tid] == 0u) ? 1u : 0u) | ((cntall[tid + 64] == 0u) ? 1u : 0u);
      c += __shfl_down(c, 32); e |= __shfl_down(e, 32);
      c += __shfl_down(c, 16); e |= __shfl_down(e, 16);
      c += __shfl_down(c, 8);  e |= __shfl_down(e, 8);
      c += __shfl_down(c, 4);  e |= __shfl_down(e, 4);
      c += __shfl_down(c, 2);  e |= __shfl_down(e, 2);
      c += __shfl_down(c, 1);  e |= __shfl_down(e, 1);
      if (tid == 0){ sh_chg = c; sh_empty = e; }
    }
    __syncthreads();
    if (sh_chg == 0u) break;   // global convergence: state frozen (matches reference)

    { const float4* src = (const float4*)(Psum + (size_t)(((par*4)+b)*32) * 2080);
      float4* p4 = (float4*)part;
      for (int i = tid; i < 520; i += 256){
        float4 s = make_float4(0.f, 0.f, 0.f, 0.f);
        for (int bl = 0; bl < 32; bl++){
          float4 v = src[bl*520 + i];
          s.x += v.x; s.y += v.y; s.z += v.z; s.w += v.w;
        }
        p4[i] = s;
      } }
    __syncthreads();

    if (sh_empty){
      // empty-cluster replacement: X rows j (=cluster idx) replaced BEFORE C update,
      // weights/assignments from pre-replacement X. All blocks apply identical fixup.
      u32 g0, g1; tf2x32(kl0, kl1, 0u, (u32)t, g0, g1);   // fold_in(k_loop, t)
      for (int k = 0; k < 32; k++){
        if (cntall[b*32 + k] != 0u) continue;
        int j = b*32 + k;
        u32 y0, y1; tf2x32(g0, g1, 0u, (u32)j, y0, y1);   // partitionable bits: y0^y1
        u32 ridx = (y0 ^ y1) & 8191u;
        u32 mj = maskh[par*128 + b*32 + k];
        float wj = expf(LW[b*Nn + k]);
        if (tid < 64){
          float xo = XH[(b*32 + k)*64 + tid];
          float xn = (ridx < 32u) ? XH[(b*32 + (int)ridx)*64 + tid]
                                  : E[(size_t)(b*Nn + (int)ridx)*Dd + tid];
          newX[k*64 + tid] = xn;
          float dxw = wj * (xn - xo);
          u32 m2 = mj;
          while (m2){ int kq = __ffs(m2) - 1; m2 &= m2 - 1; part[tid*32 + kq] += dxw; }
        }
      }
      __syncthreads();
      grid_barrier(bar);      // all fixup reads of old Xhead complete before writes
      if (blk == 0){
        for (int k = 0; k < 32; k++){
          if (cntall[b*32 + k] != 0u) continue;
          if (tid < 64) XH[(b*32 + k)*64 + tid] = newX[k*64 + tid];
        }
        __syncthreads();
        if (tid < 32 && cntall[b*32 + tid] == 0u){
          #pragma unroll
          for (int d2 = 0; d2 < 64; d2++) x[d2] = newX[tid*64 + d2];
          CALC_XX();
        }
      }
    }
    __syncthreads();
    // C_new = sums / clip(W, 1e-12)  (empty -> 0, matching reference)
    for (int i = tid; i < 2048; i += 256){
      int k = i >> 6, d = i & 63;
      Cl[i] = part[d*32 + k] / fmaxf(part[2048 + k], 1e-12f);
    }
    __syncthreads();
    if (tid < 32){ float s=0.f; const float* cr=&Cl[tid*64];
      #pragma unroll
      for (int d2=0; d2<64; d2++) s += cr[d2]*cr[d2];
      ccl[tid]=s; }
    __syncthreads();
  }

  // ---------- finalize 1: Dm with final C; ass from LAST assignment; partial mins/obj ----------
  CALC_DIST();
  float mind = dloc[0];
  #pragma unroll
  for (int k=1;k<32;k++) mind = fminf(mind, dloc[k]);
  #pragma unroll
  for (int k=0;k<32;k++) Dm[(size_t)(b*32 + k)*Nn + n] = dloc[k];
  { float4* dst = (float4*)(out + (size_t)(b*Nn + n)*32);
    #pragma unroll
    for (int q=0;q<8;q++){
      float4 v;
      v.x = ((prevmask>>(4*q  ))&1u) ? 1.f : 0.f;
      v.y = ((prevmask>>(4*q+1))&1u) ? 1.f : 0.f;
      v.z = ((prevmask>>(4*q+2))&1u) ? 1.f : 0.f;
      v.w = ((prevmask>>(4*q+3))&1u) ? 1.f : 0.f;
      dst[q] = v;
    } }
  if (tid < 32) kminl[tid] = ~0ull;
  red[tid] = mind;
  __syncthreads();
  #pragma unroll
  for (int k=0;k<32;k++){
    u32 u = __float_as_uint(dloc[k]);
    u = (u & 0x80000000u) ? ~u : (u | 0x80000000u);  // monotone encode (handles negatives)
    u64 pk = ((u64)u << 32) | (u32)n;                // tie -> smaller n (first argmin)
    atomicMin(&kminl[k], pk);
  }
  for (int s2 = 128; s2 > 0; s2 >>= 1){
    if (tid < s2) red[tid] += red[tid + s2];
    __syncthreads();
  }
  if (tid < 32) Pmin[(size_t)(b*32 + tid)*32 + blk] = kminl[tid];
  if (tid == 0) Pobj[b*32 + blk] = red[0];
  grid_barrier(bar);

  // ---------- finalize 2: block -> (b2,k2): rep_idx, rep, C, obj ----------
  {
    const int b2 = bid >> 5, k2 = bid & 31;
    const size_t OFF_C    = (size_t)Bb*Nn*Kk;        // 1048576
    const size_t OFF_REP  = OFF_C + (size_t)Bb*Kk*Dd;
    const size_t OFF_RIDX = OFF_REP + (size_t)Bb*Kk*Dd;
    const size_t OFF_OBJ  = OFF_RIDX + (size_t)Bb*Kk;
    if (tid == 0){
      u64 m = ~0ull;
      for (int bl = 0; bl < 32; bl++){ u64 v = Pmin[(size_t)(b2*32 + k2)*32 + bl]; if (v < m) m = v; }
      u32 enc = (u32)(m >> 32);
      u32 ub  = (enc & 0x80000000u) ? (enc & 0x7fffffffu) : ~enc;
      sh_mind = __uint_as_float(ub);
      sh_idx  = (u32)(m & 0xffffffffu);
      sh_tcnt = 0u;
    }
    if (tid < 64) newX[tid] = 0.f;   // rep accumulator
    __syncthreads();
    float mr = sh_mind;
    for (int nn = tid; nn < Nn; nn += 256){
      float dv = Dm[(size_t)(b2*32 + k2)*Nn + nn];
      if (fabsf(dv - mr) < 1e-8f){
        atomicAdd(&sh_tcnt, 1u);
        const float* xr = (nn < 32) ? &XH[(b2*32 + nn)*64] : &E[(size_t)(b2*Nn + nn)*Dd];
        for (int d2 = 0; d2 < 64; d2++) atomicAdd(&newX[d2], xr[d2]);
      }
    }
    __syncthreads();
    if (tid < 64){
      out[OFF_C   + (size_t)(b2*32 + k2)*64 + tid] = Cl[k2*64 + tid];
      out[OFF_REP + (size_t)(b2*32 + k2)*64 + tid] = newX[tid] / (float)sh_tcnt;
    }
    if (tid == 0) out[OFF_RIDX + b2*32 + k2] = (float)sh_idx;
    if (k2 == 0){
      if (tid < 32) red[tid] = Pobj[b2*32 + tid];
      __syncthreads();
      if (tid == 0){ float s = 0.f; for (int i2 = 0; i2 < 32; i2++) s += red[i2];
        out[OFF_OBJ + b2] = s / (float)Nn; }
    }
  }
}

extern "C" void kernel_launch(void* const* d_in, const int* in_sizes, int n_in,
                              void* d_out, int out_size, void* d_ws, size_t ws_size,
                              hipStream_t stream) {
  const float* E  = (const float*)d_in[0];
  const float* LW = (const float*)d_in[1];
  float* out = (float*)d_out;
  char*  ws  = (char*)d_ws;
  (void)in_sizes; (void)n_in; (void)out_size; (void)ws_size;
  kinit<<<dim3(1),    dim3(1024), 0, stream>>>(E, ws);
  kmain<<<dim3(NBLK), dim3(256),  0, stream>>>(E, LW, out, ws);
}

// Round 6
// 1917.470 us; speedup vs baseline: 2.6524x; 1.1991x over previous
//
#include <hip/hip_runtime.h>
#include <stdint.h>

typedef unsigned int u32;
typedef unsigned long long u64;

#define Bb 4
#define Nn 8192
#define Dd 64
#define Kk 32
#define MAXIT 30
#define NBLK 128   // 4 batches x 32 blocks, 256 threads = 1 point/thread

// ---- workspace layout (bytes); total ~6.35 MB ----
enum : u32 {
  WS_BAR   = 0u,        // 2 u32 barrier state (zeroed by kinit)
  WS_SEL   = 64u,       // 32 u32
  WS_MASKH = 192u,      // [par][4*32] u32 masks of head points
  WS_C0    = 1280u,     // 4*32*64 f
  WS_XHEAD = 34048u,    // 4*32*64 f  (mutable first-32 rows of X)
  WS_KEYS1 = 66816u,    // 8192 u32
  WS_KEYS2 = 99584u,
  WS_A1K   = 132352u,   // sorted (key,idx) round 1
  WS_A1V   = 165120u,
  WS_A2K   = 197888u,
  WS_A2V   = 230656u,
  WS_PCHG  = 263424u,   // [par][128] u32
  WS_PCNT  = 264448u,   // [par][4][32][32] u32
  WS_POBJ  = 297216u,   // [4][32] f
  WS_PMIN  = 297728u,   // [4][32 k][32 blk] u64 packed (dist,idx)
  WS_PSUM  = 330496u,   // [par][4][32][2080] f  (2048 sums d-major + 32 W)
  WS_DM    = 2460416u   // [4][32][8192] f final distances
};

// Threefry-2x32, 20 rounds — matches jax._src.prng
__device__ __forceinline__ void tf2x32(u32 k0, u32 k1, u32 x0, u32 x1, u32& o0, u32& o1){
  u32 ks2 = k0 ^ k1 ^ 0x1BD11BDAu;
  x0 += k0; x1 += k1;
#define TFR(r) { x0 += x1; x1 = (x1<<(r))|(x1>>(32-(r))); x1 ^= x0; }
  TFR(13) TFR(15) TFR(26) TFR(6)
  x0 += k1;  x1 += ks2 + 1u;
  TFR(17) TFR(29) TFR(16) TFR(24)
  x0 += ks2; x1 += k0 + 2u;
  TFR(13) TFR(15) TFR(26) TFR(6)
  x0 += k0;  x1 += k1 + 3u;
  TFR(17) TFR(29) TFR(16) TFR(24)
  x0 += k1;  x1 += ks2 + 4u;
  TFR(13) TFR(15) TFR(26) TFR(6)
  x0 += ks2; x1 += k0 + 5u;
#undef TFR
  o0 = x0; o1 = x1;
}

// ---------------- init kernel: PRNG + 2 stable sorts + C0/Xhead/barrier init ----
__global__ __launch_bounds__(1024, 1) void kinit(const float* __restrict__ E, char* __restrict__ ws){
  const int tid = threadIdx.x;
  u32* bar   = (u32*)(ws + WS_BAR);
  u32* sel   = (u32*)(ws + WS_SEL);
  u32* keys1 = (u32*)(ws + WS_KEYS1);
  u32* keys2 = (u32*)(ws + WS_KEYS2);
  u32* a1k = (u32*)(ws + WS_A1K); u32* a1v = (u32*)(ws + WS_A1V);
  u32* a2k = (u32*)(ws + WS_A2K); u32* a2v = (u32*)(ws + WS_A2V);
  float* C0 = (float*)(ws + WS_C0);
  float* XH = (float*)(ws + WS_XHEAD);

  __shared__ u32 hist[8192];
  __shared__ u32 lsum[1024];
  __shared__ u32 sel_s[32];

  if (tid < 4) bar[tid] = 0u;

  // key chain (threefry_partitionable=True semantics):
  // root=(0,42); k_init = enc_root(0,0)
  u32 i0,i1; tf2x32(0u,42u, 0u,0u, i0,i1);
  // round1: key1 = enc_kinit(0,0); sub1 = enc_kinit(0,1)
  u32 key10,key11, s10,s11;
  tf2x32(i0,i1, 0u,0u, key10,key11);
  tf2x32(i0,i1, 0u,1u, s10,s11);
  // round2: sub2 = enc_key1(0,1)
  u32 s20,s21; tf2x32(key10,key11, 0u,1u, s20,s21);

  // sort keys: bits32 = y0 ^ y1 of enc_sub(0, i)   (partitionable random_bits)
  for (int i = tid; i < 8192; i += 1024){
    u32 y0,y1;
    tf2x32(s10,s11, 0u,(u32)i, y0,y1); keys1[i] = y0 ^ y1;
    tf2x32(s20,s21, 0u,(u32)i, y0,y1); keys2[i] = y0 ^ y1;
  }
  // Xhead = first 32 rows of each batch
  for (int i = tid; i < 8192; i += 1024){
    int b = i >> 11; int rem = i & 2047;
    XH[i] = E[(size_t)b*Nn*Dd + rem];
  }
  __syncthreads();

  // two stable sorts: bucket by top 13 bits, insertion-sort buckets by (key, idx)
  for (int rnd = 0; rnd < 2; rnd++){
    u32* keys = rnd ? keys2 : keys1;
    u32* ak   = rnd ? a2k   : a1k;
    u32* av   = rnd ? a2v   : a1v;
    for (int i = tid; i < 8192; i += 1024) hist[i] = 0u;
    __syncthreads();
    for (int i = tid; i < 8192; i += 1024) atomicAdd(&hist[keys[i]>>19], 1u);
    __syncthreads();
    // exclusive scan of 8192 buckets
    { u32 s = 0;
      for (int j = 0; j < 8; j++) s += hist[tid*8+j];
      lsum[tid] = s; }
    __syncthreads();
    for (int st = 1; st < 1024; st <<= 1){
      u32 v = (tid >= st) ? lsum[tid-st] : 0u;
      __syncthreads();
      lsum[tid] += v;
      __syncthreads();
    }
    { u32 run = tid ? lsum[tid-1] : 0u;
      for (int j = 0; j < 8; j++){ u32 c = hist[tid*8+j]; hist[tid*8+j] = run; run += c; } }
    __syncthreads();
    // scatter (hist becomes end-offsets)
    for (int i = tid; i < 8192; i += 1024){
      u32 kx = keys[i];
      u32 pos = atomicAdd(&hist[kx>>19], 1u);
      ak[pos] = kx; av[pos] = (u32)i;
    }
    __syncthreads();
    // per-bucket insertion sort -> total order == stable sort by key
    for (int bkt = tid; bkt < 8192; bkt += 1024){
      int s0 = bkt ? (int)hist[bkt-1] : 0;
      int e0 = (int)hist[bkt];
      for (int i = s0+1; i < e0; i++){
        u32 kx = ak[i], vx = av[i];
        int j = i-1;
        while (j >= s0 && (ak[j] > kx || (ak[j] == kx && av[j] > vx))){
          ak[j+1] = ak[j]; av[j+1] = av[j]; j--;
        }
        ak[j+1] = kx; av[j+1] = vx;
      }
    }
    __syncthreads();
  }
  // sel[j] = perm2[j] = perm1[pos of j-th smallest keys2]
  if (tid < 32){ u32 p = a2v[tid]; u32 sj = a1v[p]; sel[tid] = sj; sel_s[tid] = sj; }
  __syncthreads();
  // C0[b][k][d] = E[b][sel[k]][d]
  for (int i = tid; i < 8192; i += 1024){
    int b = i >> 11; int k = (i >> 6) & 31; int d = i & 63;
    C0[i] = E[(size_t)b*Nn*Dd + (size_t)sel_s[k]*Dd + d];
  }
}

// device-scope sense-reversing grid barrier (128 co-resident blocks)
// Fence-minimal protocol: RELEASE arrival RMW, RELAXED spin (ACQUIRE hedge every
// 64 polls), single ACQUIRE agent fence on wake.
__device__ __forceinline__ void grid_barrier(u32* bar){
  __syncthreads();
  if (threadIdx.x == 0){
    u32 g = __hip_atomic_load(&bar[1], __ATOMIC_RELAXED, __HIP_MEMORY_SCOPE_AGENT);
    u32 a = __hip_atomic_fetch_add(&bar[0], 1u, __ATOMIC_RELEASE, __HIP_MEMORY_SCOPE_AGENT);
    if (a == (u32)(NBLK-1)){
      __hip_atomic_store(&bar[0], 0u, __ATOMIC_RELAXED, __HIP_MEMORY_SCOPE_AGENT);
      __hip_atomic_store(&bar[1], g + 1u, __ATOMIC_RELEASE, __HIP_MEMORY_SCOPE_AGENT);
    } else {
      int polls = 0;
      for (;;){
        u32 v = __hip_atomic_load(&bar[1], __ATOMIC_RELAXED, __HIP_MEMORY_SCOPE_AGENT);
        if (v != g) break;
        if ((++polls & 63) == 0){
          v = __hip_atomic_load(&bar[1], __ATOMIC_ACQUIRE, __HIP_MEMORY_SCOPE_AGENT);
          if (v != g) break;
        }
        __builtin_amdgcn_s_sleep(2);
      }
    }
    __builtin_amdgcn_fence(__ATOMIC_ACQUIRE, "agent");
  }
  __syncthreads();
}

#define CALC_XX() do { float s0=0.f,s1=0.f,s2=0.f,s3=0.f; \
  _Pragma("unroll") \
  for (int j=0;j<16;j++){ s0+=x[4*j]*x[4*j]; s1+=x[4*j+1]*x[4*j+1]; s2+=x[4*j+2]*x[4*j+2]; s3+=x[4*j+3]*x[4*j+3]; } \
  xx=(s0+s1)+(s2+s3); } while(0)

#define CALC_DIST() do { \
  _Pragma("unroll") \
  for (int k=0;k<32;k++){ \
    const float4* cp = (const float4*)&Cl[k*64]; \
    float s0=0.f,s1=0.f,s2=0.f,s3=0.f; \
    _Pragma("unroll") \
    for (int j=0;j<16;j++){ float4 c = cp[j]; s0+=x[4*j]*c.x; s1+=x[4*j+1]*c.y; s2+=x[4*j+2]*c.z; s3+=x[4*j+3]*c.w; } \
    float dot=(s0+s1)+(s2+s3); \
    dloc[k]=(ccl[k]+xx)-2.f*dot; \
  } } while(0)

__global__ __launch_bounds__(256, 1) void kmain(const float* __restrict__ E, const float* __restrict__ LW,
                                                float* __restrict__ out, char* __restrict__ ws){
  const int tid = threadIdx.x;
  const int bid = blockIdx.x;
  const int b   = bid >> 5;
  const int blk = bid & 31;
  const int n   = (blk << 8) + tid;

  u32*   bar   = (u32*)(ws + WS_BAR);
  u32*   maskh = (u32*)(ws + WS_MASKH);
  float* C0    = (float*)(ws + WS_C0);
  float* XH    = (float*)(ws + WS_XHEAD);
  u32*   Pchg  = (u32*)(ws + WS_PCHG);
  u32*   Pcnt  = (u32*)(ws + WS_PCNT);
  float* Pobj  = (float*)(ws + WS_POBJ);
  u64*   Pmin  = (u64*)(ws + WS_PMIN);
  float* Psum  = (float*)(ws + WS_PSUM);
  float* Dm    = (float*)(ws + WS_DM);

  __shared__ float Cl[2048];      // C[k][d] (k-major, float4 broadcast reads)
  __shared__ float ccl[32];
  __shared__ float part[2080];    // sums d-major: part[d*32+k]; W at part[2048+k]
  __shared__ u32   cntl[32];
  __shared__ u32   cntall[128];   // reduced counts, all batches
  __shared__ u32   chg_s[128];
  __shared__ float newX[2048];    // replacement rows staging / rep accumulator
  __shared__ u64   kminl[32];
  __shared__ float red[256];
  __shared__ u32   sh_chg, sh_empty, sh_idx, sh_tcnt;
  __shared__ float sh_mind;

  // load this thread's point into registers
  float x[64]; float xx;
  { const float4* xr = (const float4*)(E + (size_t)(b*Nn + n)*Dd);
    #pragma unroll
    for (int j=0;j<16;j++){ float4 v = xr[j]; x[4*j]=v.x; x[4*j+1]=v.y; x[4*j+2]=v.z; x[4*j+3]=v.w; } }
  CALC_XX();
  const float w = expf(LW[b*Nn + n]);  // weight is positional, constant

  // k_loop = enc_(0,42)(0,1)  (for empty-cluster randint path)
  u32 kl0, kl1; tf2x32(0u,42u, 0u,1u, kl0, kl1);

  for (int i = tid; i < 2048; i += 256) Cl[i] = C0[b*2048 + i];
  __syncthreads();
  if (tid < 32){ float s=0.f; const float* cr=&Cl[tid*64];
    #pragma unroll
    for (int d2=0; d2<64; d2++) s += cr[d2]*cr[d2];
    ccl[tid]=s; }
  __syncthreads();

  u32 prevmask = 0u;
  float dloc[32];

  for (int t = 0; t < MAXIT; t++){
    const int par = t & 1;
    // ---------- phase 1: assignment + per-block partial sums ----------
    CALC_DIST();
    float mind = dloc[0];
    #pragma unroll
    for (int k=1;k<32;k++) mind = fminf(mind, dloc[k]);
    u32 mask = 0u;
    #pragma unroll
    for (int k=0;k<32;k++) if (fabsf(dloc[k]-mind) < 1e-8f) mask |= (1u<<k);
    int changed = (t==0) ? 1 : (mask != prevmask);
    prevmask = mask;
    if (blk == 0 && tid < 32) maskh[par*128 + b*32 + tid] = mask;

    __syncthreads();
    for (int i = tid; i < 2080; i += 256) part[i] = 0.f;
    if (tid < 32) cntl[tid] = 0u;
    __syncthreads();
    { u32 mm = mask;
      while (mm){
        int k = __ffs(mm) - 1; mm &= mm - 1;
        #pragma unroll
        for (int d2=0; d2<64; d2++) atomicAdd(&part[d2*32 + k], w*x[d2]);
        atomicAdd(&part[2048 + k], w);
        atomicAdd(&cntl[k], 1u);
      } }
    int nchg = __syncthreads_count(changed);
    { float* dst = Psum + (size_t)(((par*4)+b)*32 + blk) * 2080;
      for (int i = tid; i < 2080; i += 256) dst[i] = part[i];
      if (tid < 32) Pcnt[(((par*4)+b)*32 + blk)*32 + tid] = cntl[tid];
      if (tid == 0) Pchg[par*128 + bid] = (u32)nchg; }
    grid_barrier(bar);

    // ---------- phase 2: every block reduces -> its own C in LDS ----------
    if (tid < 128){
      u32 s = 0; int bb = tid >> 5, kq = tid & 31;
      for (int bl = 0; bl < 32; bl++) s += Pcnt[(((par*4)+bb)*32 + bl)*32 + kq];
      cntall[tid] = s;
      chg_s[tid] = Pchg[par*128 + tid];
    }
    __syncthreads();
    // parallel chg-sum + empty-OR over the 128 entries (bit-identical to the
    // old tid0 serial loop; integer-only, removes ~128 serialized LDS reads)
    if (tid < 64){
      u32 c = chg_s[tid] + chg_s[tid + 64];
      u32 e = ((cntall[tid] == 0u) ? 1u : 0u) | ((cntall[tid + 64] == 0u) ? 1u : 0u);
      c += __shfl_down(c, 32); e |= __shfl_down(e, 32);
      c += __shfl_down(c, 16); e |= __shfl_down(e, 16);
      c += __shfl_down(c, 8);  e |= __shfl_down(e, 8);
      c += __shfl_down(c, 4);  e |= __shfl_down(e, 4);
      c += __shfl_down(c, 2);  e |= __shfl_down(e, 2);
      c += __shfl_down(c, 1);  e |= __shfl_down(e, 1);
      if (tid == 0){ sh_chg = c; sh_empty = e; }
    }
    __syncthreads();
    if (sh_chg == 0u) break;   // global convergence: state frozen (matches reference)

    { const float* src = Psum + (size_t)(((par*4)+b)*32) * 2080;
      for (int i = tid; i < 2080; i += 256){
        float s = 0.f;
        for (int bl = 0; bl < 32; bl++) s += src[bl*2080 + i];
        part[i] = s;
      } }
    __syncthreads();

    if (sh_empty){
      // empty-cluster replacement: X rows j (=cluster idx) replaced BEFORE C update,
      // weights/assignments from pre-replacement X. All blocks apply identical fixup.
      u32 g0, g1; tf2x32(kl0, kl1, 0u, (u32)t, g0, g1);   // fold_in(k_loop, t)
      for (int k = 0; k < 32; k++){
        if (cntall[b*32 + k] != 0u) continue;
        int j = b*32 + k;
        u32 y0, y1; tf2x32(g0, g1, 0u, (u32)j, y0, y1);   // partitionable bits: y0^y1
        u32 ridx = (y0 ^ y1) & 8191u;
        u32 mj = maskh[par*128 + b*32 + k];
        float wj = expf(LW[b*Nn + k]);
        if (tid < 64){
          float xo = XH[(b*32 + k)*64 + tid];
          float xn = (ridx < 32u) ? XH[(b*32 + (int)ridx)*64 + tid]
                                  : E[(size_t)(b*Nn + (int)ridx)*Dd + tid];
          newX[k*64 + tid] = xn;
          float dxw = wj * (xn - xo);
          u32 m2 = mj;
          while (m2){ int kq = __ffs(m2) - 1; m2 &= m2 - 1; part[tid*32 + kq] += dxw; }
        }
      }
      __syncthreads();
      grid_barrier(bar);      // all fixup reads of old Xhead complete before writes
      if (blk == 0){
        for (int k = 0; k < 32; k++){
          if (cntall[b*32 + k] != 0u) continue;
          if (tid < 64) XH[(b*32 + k)*64 + tid] = newX[k*64 + tid];
        }
        __syncthreads();
        if (tid < 32 && cntall[b*32 + tid] == 0u){
          #pragma unroll
          for (int d2 = 0; d2 < 64; d2++) x[d2] = newX[tid*64 + d2];
          CALC_XX();
        }
      }
    }
    __syncthreads();
    // C_new = sums / clip(W, 1e-12)  (empty -> 0, matching reference)
    for (int i = tid; i < 2048; i += 256){
      int k = i >> 6, d = i & 63;
      Cl[i] = part[d*32 + k] / fmaxf(part[2048 + k], 1e-12f);
    }
    __syncthreads();
    if (tid < 32){ float s=0.f; const float* cr=&Cl[tid*64];
      #pragma unroll
      for (int d2=0; d2<64; d2++) s += cr[d2]*cr[d2];
      ccl[tid]=s; }
    __syncthreads();
  }

  // ---------- finalize 1: Dm with final C; ass from LAST assignment; partial mins/obj ----------
  CALC_DIST();
  float mind = dloc[0];
  #pragma unroll
  for (int k=1;k<32;k++) mind = fminf(mind, dloc[k]);
  #pragma unroll
  for (int k=0;k<32;k++) Dm[(size_t)(b*32 + k)*Nn + n] = dloc[k];
  { float4* dst = (float4*)(out + (size_t)(b*Nn + n)*32);
    #pragma unroll
    for (int q=0;q<8;q++){
      float4 v;
      v.x = ((prevmask>>(4*q  ))&1u) ? 1.f : 0.f;
      v.y = ((prevmask>>(4*q+1))&1u) ? 1.f : 0.f;
      v.z = ((prevmask>>(4*q+2))&1u) ? 1.f : 0.f;
      v.w = ((prevmask>>(4*q+3))&1u) ? 1.f : 0.f;
      dst[q] = v;
    } }
  if (tid < 32) kminl[tid] = ~0ull;
  red[tid] = mind;
  __syncthreads();
  #pragma unroll
  for (int k=0;k<32;k++){
    u32 u = __float_as_uint(dloc[k]);
    u = (u & 0x80000000u) ? ~u : (u | 0x80000000u);  // monotone encode (handles negatives)
    u64 pk = ((u64)u << 32) | (u32)n;                // tie -> smaller n (first argmin)
    atomicMin(&kminl[k], pk);
  }
  for (int s2 = 128; s2 > 0; s2 >>= 1){
    if (tid < s2) red[tid] += red[tid + s2];
    __syncthreads();
  }
  if (tid < 32) Pmin[(size_t)(b*32 + tid)*32 + blk] = kminl[tid];
  if (tid == 0) Pobj[b*32 + blk] = red[0];
  grid_barrier(bar);

  // ---------- finalize 2: block -> (b2,k2): rep_idx, rep, C, obj ----------
  {
    const int b2 = bid >> 5, k2 = bid & 31;
    const size_t OFF_C    = (size_t)Bb*Nn*Kk;        // 1048576
    const size_t OFF_REP  = OFF_C + (size_t)Bb*Kk*Dd;
    const size_t OFF_RIDX = OFF_REP + (size_t)Bb*Kk*Dd;
    const size_t OFF_OBJ  = OFF_RIDX + (size_t)Bb*Kk;
    if (tid == 0){
      u64 m = ~0ull;
      for (int bl = 0; bl < 32; bl++){ u64 v = Pmin[(size_t)(b2*32 + k2)*32 + bl]; if (v < m) m = v; }
      u32 enc = (u32)(m >> 32);
      u32 ub  = (enc & 0x80000000u) ? (enc & 0x7fffffffu) : ~enc;
      sh_mind = __uint_as_float(ub);
      sh_idx  = (u32)(m & 0xffffffffu);
      sh_tcnt = 0u;
    }
    if (tid < 64) newX[tid] = 0.f;   // rep accumulator
    __syncthreads();
    float mr = sh_mind;
    for (int nn = tid; nn < Nn; nn += 256){
      float dv = Dm[(size_t)(b2*32 + k2)*Nn + nn];
      if (fabsf(dv - mr) < 1e-8f){
        atomicAdd(&sh_tcnt, 1u);
        const float* xr = (nn < 32) ? &XH[(b2*32 + nn)*64] : &E[(size_t)(b2*Nn + nn)*Dd];
        for (int d2 = 0; d2 < 64; d2++) atomicAdd(&newX[d2], xr[d2]);
      }
    }
    __syncthreads();
    if (tid < 64){
      out[OFF_C   + (size_t)(b2*32 + k2)*64 + tid] = Cl[k2*64 + tid];
      out[OFF_REP + (size_t)(b2*32 + k2)*64 + tid] = newX[tid] / (float)sh_tcnt;
    }
    if (tid == 0) out[OFF_RIDX + b2*32 + k2] = (float)sh_idx;
    if (k2 == 0){
      if (tid < 32) red[tid] = Pobj[b2*32 + tid];
      __syncthreads();
      if (tid == 0){ float s = 0.f; for (int i2 = 0; i2 < 32; i2++) s += red[i2];
        out[OFF_OBJ + b2] = s / (float)Nn; }
    }
  }
}

extern "C" void kernel_launch(void* const* d_in, const int* in_sizes, int n_in,
                              void* d_out, int out_size, void* d_ws, size_t ws_size,
                              hipStream_t stream) {
  const float* E  = (const float*)d_in[0];
  const float* LW = (const float*)d_in[1];
  float* out = (float*)d_out;
  char*  ws  = (char*)d_ws;
  (void)in_sizes; (void)n_in; (void)out_size; (void)ws_size;
  kinit<<<dim3(1),    dim3(1024), 0, stream>>>(E, ws);
  kmain<<<dim3(NBLK), dim3(256),  0, stream>>>(E, LW, out, ws);
}

// Round 7
// 1582.502 us; speedup vs baseline: 3.2138x; 1.2117x over previous
//
#include <hip/hip_runtime.h>
#include <stdint.h>

typedef unsigned int u32;
typedef unsigned long long u64;

#define Bb 4
#define Nn 8192
#define Dd 64
#define Kk 32
#define MAXIT 30
#define NBLK 256   // 4 batches x 64 blocks, 128 threads = 1 point/thread (all 256 CUs)
#define RPB  64    // blocks per batch

// ---- workspace layout (bytes) ----
enum : u32 {
  WS_BAR   = 0u,         // barrier state (zeroed by kinit)
  WS_SEL   = 64u,        // 32 u32
  WS_MASKH = 192u,       // [par][4*32] u32 masks of head points
  WS_C0    = 1280u,      // 4*32*64 f (ends 34048)
  WS_XHEAD = 34048u,     // 4*32*64 f (ends 66816)
  WS_KEYS1 = 66816u,     // kinit sort scratch
  WS_KEYS2 = 99584u,
  WS_A1K   = 132352u,
  WS_A1V   = 165120u,
  WS_A2K   = 197888u,
  WS_A2V   = 230656u,    // ends 263424
  WS_ACC   = 263424u,    // 3 x [4][2112] f accumulators (2048 sums d-major + 32 W + 32 cnt)
                         // ends 263424 + 3*4*2112*4 = 364800
  WS_CHG   = 364800u,    // 3 f (global changed-count per buffer) ; pad to 64
  WS_POBJ  = 364864u,    // [4][64] f
  WS_PMIN  = 365888u,    // [4][32 k][64 blk] u64 packed (dist,idx) (ends 431424)
  WS_DM    = 431424u     // [4][32][8192] f final distances (ends 4625728)
};

#define ACC_STRIDE 2112  // floats per batch accumulator

// Threefry-2x32, 20 rounds — matches jax._src.prng
__device__ __forceinline__ void tf2x32(u32 k0, u32 k1, u32 x0, u32 x1, u32& o0, u32& o1){
  u32 ks2 = k0 ^ k1 ^ 0x1BD11BDAu;
  x0 += k0; x1 += k1;
#define TFR(r) { x0 += x1; x1 = (x1<<(r))|(x1>>(32-(r))); x1 ^= x0; }
  TFR(13) TFR(15) TFR(26) TFR(6)
  x0 += k1;  x1 += ks2 + 1u;
  TFR(17) TFR(29) TFR(16) TFR(24)
  x0 += ks2; x1 += k0 + 2u;
  TFR(13) TFR(15) TFR(26) TFR(6)
  x0 += k0;  x1 += k1 + 3u;
  TFR(17) TFR(29) TFR(16) TFR(24)
  x0 += k1;  x1 += ks2 + 4u;
  TFR(13) TFR(15) TFR(26) TFR(6)
  x0 += ks2; x1 += k0 + 5u;
#undef TFR
  o0 = x0; o1 = x1;
}

// ---------------- init kernel: PRNG + 2 stable sorts + C0/Xhead/acc/barrier init ----
__global__ __launch_bounds__(1024, 1) void kinit(const float* __restrict__ E, char* __restrict__ ws){
  const int tid = threadIdx.x;
  u32* bar   = (u32*)(ws + WS_BAR);
  u32* sel   = (u32*)(ws + WS_SEL);
  u32* keys1 = (u32*)(ws + WS_KEYS1);
  u32* keys2 = (u32*)(ws + WS_KEYS2);
  u32* a1k = (u32*)(ws + WS_A1K); u32* a1v = (u32*)(ws + WS_A1V);
  u32* a2k = (u32*)(ws + WS_A2K); u32* a2v = (u32*)(ws + WS_A2V);
  float* C0 = (float*)(ws + WS_C0);
  float* XH = (float*)(ws + WS_XHEAD);
  float* ACC0 = (float*)(ws + WS_ACC);
  float* CHG  = (float*)(ws + WS_CHG);

  __shared__ u32 hist[8192];
  __shared__ u32 lsum[1024];
  __shared__ u32 sel_s[32];

  if (tid < 4) bar[tid] = 0u;
  if (tid < 3) CHG[tid] = 0.f;
  for (int i = tid; i < Bb*ACC_STRIDE; i += 1024) ACC0[i] = 0.f;  // buffer 0 for t=0

  // key chain (threefry_partitionable=True semantics):
  // root=(0,42); k_init = enc_root(0,0)
  u32 i0,i1; tf2x32(0u,42u, 0u,0u, i0,i1);
  u32 key10,key11, s10,s11;
  tf2x32(i0,i1, 0u,0u, key10,key11);
  tf2x32(i0,i1, 0u,1u, s10,s11);
  u32 s20,s21; tf2x32(key10,key11, 0u,1u, s20,s21);

  // sort keys: bits32 = y0 ^ y1 of enc_sub(0, i)   (partitionable random_bits)
  for (int i = tid; i < 8192; i += 1024){
    u32 y0,y1;
    tf2x32(s10,s11, 0u,(u32)i, y0,y1); keys1[i] = y0 ^ y1;
    tf2x32(s20,s21, 0u,(u32)i, y0,y1); keys2[i] = y0 ^ y1;
  }
  // Xhead = first 32 rows of each batch
  for (int i = tid; i < 8192; i += 1024){
    int b = i >> 11; int rem = i & 2047;
    XH[i] = E[(size_t)b*Nn*Dd + rem];
  }
  __syncthreads();

  // two stable sorts: bucket by top 13 bits, insertion-sort buckets by (key, idx)
  for (int rnd = 0; rnd < 2; rnd++){
    u32* keys = rnd ? keys2 : keys1;
    u32* ak   = rnd ? a2k   : a1k;
    u32* av   = rnd ? a2v   : a1v;
    for (int i = tid; i < 8192; i += 1024) hist[i] = 0u;
    __syncthreads();
    for (int i = tid; i < 8192; i += 1024) atomicAdd(&hist[keys[i]>>19], 1u);
    __syncthreads();
    { u32 s = 0;
      for (int j = 0; j < 8; j++) s += hist[tid*8+j];
      lsum[tid] = s; }
    __syncthreads();
    for (int st = 1; st < 1024; st <<= 1){
      u32 v = (tid >= st) ? lsum[tid-st] : 0u;
      __syncthreads();
      lsum[tid] += v;
      __syncthreads();
    }
    { u32 run = tid ? lsum[tid-1] : 0u;
      for (int j = 0; j < 8; j++){ u32 c = hist[tid*8+j]; hist[tid*8+j] = run; run += c; } }
    __syncthreads();
    for (int i = tid; i < 8192; i += 1024){
      u32 kx = keys[i];
      u32 pos = atomicAdd(&hist[kx>>19], 1u);
      ak[pos] = kx; av[pos] = (u32)i;
    }
    __syncthreads();
    for (int bkt = tid; bkt < 8192; bkt += 1024){
      int s0 = bkt ? (int)hist[bkt-1] : 0;
      int e0 = (int)hist[bkt];
      for (int i = s0+1; i < e0; i++){
        u32 kx = ak[i], vx = av[i];
        int j = i-1;
        while (j >= s0 && (ak[j] > kx || (ak[j] == kx && av[j] > vx))){
          ak[j+1] = ak[j]; av[j+1] = av[j]; j--;
        }
        ak[j+1] = kx; av[j+1] = vx;
      }
    }
    __syncthreads();
  }
  if (tid < 32){ u32 p = a2v[tid]; u32 sj = a1v[p]; sel[tid] = sj; sel_s[tid] = sj; }
  __syncthreads();
  for (int i = tid; i < 8192; i += 1024){
    int b = i >> 11; int k = (i >> 6) & 31; int d = i & 63;
    C0[i] = E[(size_t)b*Nn*Dd + (size_t)sel_s[k]*Dd + d];
  }
}

// device-scope sense-reversing grid barrier (256 co-resident blocks)
// Fence-minimal protocol: RELEASE arrival RMW, RELAXED spin (ACQUIRE hedge every
// 64 polls), single ACQUIRE agent fence on wake.
__device__ __forceinline__ void grid_barrier(u32* bar){
  __syncthreads();
  if (threadIdx.x == 0){
    u32 g = __hip_atomic_load(&bar[1], __ATOMIC_RELAXED, __HIP_MEMORY_SCOPE_AGENT);
    u32 a = __hip_atomic_fetch_add(&bar[0], 1u, __ATOMIC_RELEASE, __HIP_MEMORY_SCOPE_AGENT);
    if (a == (u32)(NBLK-1)){
      __hip_atomic_store(&bar[0], 0u, __ATOMIC_RELAXED, __HIP_MEMORY_SCOPE_AGENT);
      __hip_atomic_store(&bar[1], g + 1u, __ATOMIC_RELEASE, __HIP_MEMORY_SCOPE_AGENT);
    } else {
      int polls = 0;
      for (;;){
        u32 v = __hip_atomic_load(&bar[1], __ATOMIC_RELAXED, __HIP_MEMORY_SCOPE_AGENT);
        if (v != g) break;
        if ((++polls & 63) == 0){
          v = __hip_atomic_load(&bar[1], __ATOMIC_ACQUIRE, __HIP_MEMORY_SCOPE_AGENT);
          if (v != g) break;
        }
        __builtin_amdgcn_s_sleep(2);
      }
    }
    __builtin_amdgcn_fence(__ATOMIC_ACQUIRE, "agent");
  }
  __syncthreads();
}

#define CALC_XX() do { float s0=0.f,s1=0.f,s2=0.f,s3=0.f; \
  _Pragma("unroll") \
  for (int j=0;j<16;j++){ s0+=x[4*j]*x[4*j]; s1+=x[4*j+1]*x[4*j+1]; s2+=x[4*j+2]*x[4*j+2]; s3+=x[4*j+3]*x[4*j+3]; } \
  xx=(s0+s1)+(s2+s3); } while(0)

#define CALC_DIST() do { \
  _Pragma("unroll") \
  for (int k=0;k<32;k++){ \
    const float4* cp = (const float4*)&Cl[k*64]; \
    float s0=0.f,s1=0.f,s2=0.f,s3=0.f; \
    _Pragma("unroll") \
    for (int j=0;j<16;j++){ float4 c = cp[j]; s0+=x[4*j]*c.x; s1+=x[4*j+1]*c.y; s2+=x[4*j+2]*c.z; s3+=x[4*j+3]*c.w; } \
    float dot=(s0+s1)+(s2+s3); \
    dloc[k]=(ccl[k]+xx)-2.f*dot; \
  } } while(0)

__global__ __launch_bounds__(128, 1) void kmain(const float* __restrict__ E, const float* __restrict__ LW,
                                                float* __restrict__ out, char* __restrict__ ws){
  const int tid = threadIdx.x;
  const int bid = blockIdx.x;
  const int b   = bid >> 6;           // batch
  const int r   = bid & 63;           // block-in-batch
  const int n   = (r << 7) + tid;     // this thread's point (head rows: r==0, tid<32)

  u32*   bar   = (u32*)(ws + WS_BAR);
  u32*   maskh = (u32*)(ws + WS_MASKH);
  float* C0    = (float*)(ws + WS_C0);
  float* XH    = (float*)(ws + WS_XHEAD);
  float* ACC   = (float*)(ws + WS_ACC);
  float* CHG   = (float*)(ws + WS_CHG);
  float* Pobj  = (float*)(ws + WS_POBJ);
  u64*   Pmin  = (u64*)(ws + WS_PMIN);
  float* Dm    = (float*)(ws + WS_DM);

  __shared__ float Cl[2048];      // C[k][d] (k-major, float4 broadcast reads)
  __shared__ float ccl[32];
  __shared__ float part[ACC_STRIDE]; // [0..2047] sums d-major part[d*32+k]; [2048+k]=W; [2080+k]=cnt
  __shared__ float newX[2048];    // replacement rows staging / rep accumulator
  __shared__ u64   kminl[32];
  __shared__ float red[128];
  __shared__ u32   sh_empty, sh_idx, sh_tcnt;
  __shared__ float sh_chgf, sh_mind;

  // load this thread's point into registers
  float x[64]; float xx;
  { const float4* xr = (const float4*)(E + (size_t)(b*Nn + n)*Dd);
    #pragma unroll
    for (int j=0;j<16;j++){ float4 v = xr[j]; x[4*j]=v.x; x[4*j+1]=v.y; x[4*j+2]=v.z; x[4*j+3]=v.w; } }
  CALC_XX();
  const float w = expf(LW[b*Nn + n]);  // weight is positional, constant

  // k_loop = enc_(0,42)(0,1)  (for empty-cluster randint path)
  u32 kl0, kl1; tf2x32(0u,42u, 0u,1u, kl0, kl1);

  for (int i = tid; i < 2048; i += 128) Cl[i] = C0[b*2048 + i];
  __syncthreads();
  if (tid < 32){ float s=0.f; const float* cr=&Cl[tid*64];
    #pragma unroll
    for (int d2=0; d2<64; d2++) s += cr[d2]*cr[d2];
    ccl[tid]=s; }
  __syncthreads();

  u32 prevmask = 0u;
  float dloc[32];

  for (int t = 0; t < MAXIT; t++){
    const int par = t & 1;
    const int cur = t % 3, nxt = (t + 1) % 3;   // triple-buffered accumulators
    // ---------- phase 1: assignment + per-block partial sums ----------
    CALC_DIST();
    float mind = dloc[0];
    #pragma unroll
    for (int k=1;k<32;k++) mind = fminf(mind, dloc[k]);
    u32 mask = 0u;
    #pragma unroll
    for (int k=0;k<32;k++) if (fabsf(dloc[k]-mind) < 1e-8f) mask |= (1u<<k);
    int changed = (t==0) ? 1 : (mask != prevmask);
    prevmask = mask;
    if (r == 0 && tid < 32) maskh[par*128 + b*32 + tid] = mask;

    __syncthreads();
    for (int i = tid; i < ACC_STRIDE; i += 128) part[i] = 0.f;
    __syncthreads();
    { u32 mm = mask;
      while (mm){
        int k = __ffs(mm) - 1; mm &= mm - 1;
        #pragma unroll
        for (int d2=0; d2<64; d2++) atomicAdd(&part[d2*32 + k], w*x[d2]);
        atomicAdd(&part[2048 + k], w);
        atomicAdd(&part[2080 + k], 1.0f);   // count, exact in f32
      } }
    int nchg = __syncthreads_count(changed);
    // scatter partials into the shared per-batch accumulator (native f32 atomics),
    // zero the t+1 buffer (its last readers finished before the t-1 barrier),
    // and add this block's changed-count to the global scalar.
    { float* dst = ACC + (size_t)cur*Bb*ACC_STRIDE + b*ACC_STRIDE;
      for (int i = tid; i < ACC_STRIDE; i += 128) unsafeAtomicAdd(&dst[i], part[i]);
      if (tid == 0 && nchg) unsafeAtomicAdd(&CHG[cur], (float)nchg);
      float* nz = ACC + (size_t)nxt*Bb*ACC_STRIDE + b*ACC_STRIDE;
      if (tid < 33) nz[r*33 + tid] = 0.f;           // 64 blocks x 33 = 2112 exactly
      if (b == 0 && r == 0 && tid == 33) CHG[nxt] = 0.f;
    }
    grid_barrier(bar);

    // ---------- phase 2: read reduced sums; global convergence / empty flags ----------
    { const float* src = ACC + (size_t)cur*Bb*ACC_STRIDE;
      for (int i = tid; i < ACC_STRIDE; i += 128) part[i] = src[b*ACC_STRIDE + i];
      float cv = src[(tid >> 5)*ACC_STRIDE + 2080 + (tid & 31)];  // all 4x32 counts
      if (tid == 0) sh_chgf = CHG[cur];
      int anyempty = __syncthreads_or(cv == 0.f);   // barrier: part[] now visible
      if (sh_chgf == 0.f) break;   // global convergence: state frozen (matches reference)

      // own-batch empty mask from reduced counts
      { bool e = (tid < 32) && (part[2080 + tid] == 0.f);
        u64 bal = __ballot(e);
        if (tid == 0) sh_empty = (u32)bal; }
      __syncthreads();
      u32 em = sh_empty;

      if (anyempty){   // uniform across ALL blocks (all batches) -> barrier-safe
        // empty-cluster replacement: X rows j (=cluster idx) replaced BEFORE C update,
        // weights/assignments from pre-replacement X. Each block fixes its local copy.
        u32 g0, g1; tf2x32(kl0, kl1, 0u, (u32)t, g0, g1);   // fold_in(k_loop, t)
        for (int k = 0; k < 32; k++){
          if (!((em >> k) & 1u)) continue;
          int j = b*32 + k;
          u32 y0, y1; tf2x32(g0, g1, 0u, (u32)j, y0, y1);   // partitionable bits: y0^y1
          u32 ridx = (y0 ^ y1) & 8191u;
          u32 mj = maskh[par*128 + b*32 + k];
          float wj = expf(LW[b*Nn + k]);
          if (tid < 64){
            float xo = XH[(b*32 + k)*64 + tid];
            float xn = (ridx < 32u) ? XH[(b*32 + (int)ridx)*64 + tid]
                                    : E[(size_t)(b*Nn + (int)ridx)*Dd + tid];
            newX[k*64 + tid] = xn;
            float dxw = wj * (xn - xo);
            u32 m2 = mj;
            while (m2){ int kq = __ffs(m2) - 1; m2 &= m2 - 1; part[tid*32 + kq] += dxw; }
          }
        }
        __syncthreads();
        grid_barrier(bar);      // all fixup reads of old Xhead complete before writes
        if (r == 0){
          for (int k = 0; k < 32; k++){
            if (!((em >> k) & 1u)) continue;
            if (tid < 64) XH[(b*32 + k)*64 + tid] = newX[k*64 + tid];
          }
          __syncthreads();
          if (tid < 32 && ((em >> tid) & 1u)){
            #pragma unroll
            for (int d2 = 0; d2 < 64; d2++) x[d2] = newX[tid*64 + d2];
            CALC_XX();
          }
        }
      }
    }
    __syncthreads();
    // C_new = sums / clip(W, 1e-12)  (empty -> 0, matching reference)
    for (int i = tid; i < 2048; i += 128){
      int k = i >> 6, d = i & 63;
      Cl[i] = part[d*32 + k] / fmaxf(part[2048 + k], 1e-12f);
    }
    __syncthreads();
    if (tid < 32){ float s=0.f; const float* cr=&Cl[tid*64];
      #pragma unroll
      for (int d2=0; d2<64; d2++) s += cr[d2]*cr[d2];
      ccl[tid]=s; }
    __syncthreads();
  }

  // ---------- finalize 1: Dm with final C; ass from LAST assignment; partial mins/obj ----------
  CALC_DIST();
  float mind = dloc[0];
  #pragma unroll
  for (int k=1;k<32;k++) mind = fminf(mind, dloc[k]);
  #pragma unroll
  for (int k=0;k<32;k++) Dm[(size_t)(b*32 + k)*Nn + n] = dloc[k];
  { float4* dst = (float4*)(out + (size_t)(b*Nn + n)*32);
    #pragma unroll
    for (int q=0;q<8;q++){
      float4 v;
      v.x = ((prevmask>>(4*q  ))&1u) ? 1.f : 0.f;
      v.y = ((prevmask>>(4*q+1))&1u) ? 1.f : 0.f;
      v.z = ((prevmask>>(4*q+2))&1u) ? 1.f : 0.f;
      v.w = ((prevmask>>(4*q+3))&1u) ? 1.f : 0.f;
      dst[q] = v;
    } }
  if (tid < 32) kminl[tid] = ~0ull;
  red[tid] = mind;
  __syncthreads();
  #pragma unroll
  for (int k=0;k<32;k++){
    u32 u = __float_as_uint(dloc[k]);
    u = (u & 0x80000000u) ? ~u : (u | 0x80000000u);  // monotone encode (handles negatives)
    u64 pk = ((u64)u << 32) | (u32)n;                // tie -> smaller n (first argmin)
    atomicMin(&kminl[k], pk);
  }
  for (int s2 = 64; s2 > 0; s2 >>= 1){
    if (tid < s2) red[tid] += red[tid + s2];
    __syncthreads();
  }
  if (tid < 32) Pmin[(size_t)(b*32 + tid)*64 + r] = kminl[tid];
  if (tid == 0) Pobj[b*64 + r] = red[0];
  grid_barrier(bar);

  // ---------- finalize 2: first 128 blocks -> (b2,k2): rep_idx, rep, C, obj ----------
  if (bid < 128){
    const int b2 = bid >> 5, k2 = bid & 31;
    const size_t OFF_C    = (size_t)Bb*Nn*Kk;        // 1048576
    const size_t OFF_REP  = OFF_C + (size_t)Bb*Kk*Dd;
    const size_t OFF_RIDX = OFF_REP + (size_t)Bb*Kk*Dd;
    const size_t OFF_OBJ  = OFF_RIDX + (size_t)Bb*Kk;
    if (tid == 0){
      u64 m = ~0ull;
      for (int bl = 0; bl < 64; bl++){ u64 v = Pmin[(size_t)(b2*32 + k2)*64 + bl]; if (v < m) m = v; }
      u32 enc = (u32)(m >> 32);
      u32 ub  = (enc & 0x80000000u) ? (enc & 0x7fffffffu) : ~enc;
      sh_mind = __uint_as_float(ub);
      sh_idx  = (u32)(m & 0xffffffffu);
      sh_tcnt = 0u;
    }
    if (tid < 64) newX[tid] = 0.f;   // rep accumulator
    __syncthreads();
    float mr = sh_mind;
    for (int nn = tid; nn < Nn; nn += 128){
      float dv = Dm[(size_t)(b2*32 + k2)*Nn + nn];
      if (fabsf(dv - mr) < 1e-8f){
        atomicAdd(&sh_tcnt, 1u);
        const float* xr = (nn < 32) ? &XH[(b2*32 + nn)*64] : &E[(size_t)(b2*Nn + nn)*Dd];
        for (int d2 = 0; d2 < 64; d2++) atomicAdd(&newX[d2], xr[d2]);
      }
    }
    __syncthreads();
    if (tid < 64){
      out[OFF_C   + (size_t)(b2*32 + k2)*64 + tid] = Cl[k2*64 + tid];
      out[OFF_REP + (size_t)(b2*32 + k2)*64 + tid] = newX[tid] / (float)sh_tcnt;
    }
    if (tid == 0) out[OFF_RIDX + b2*32 + k2] = (float)sh_idx;
    if (k2 == 0){
      if (tid < 64) red[tid] = Pobj[b2*64 + tid];
      __syncthreads();
      if (tid == 0){ float s = 0.f; for (int i2 = 0; i2 < 64; i2++) s += red[i2];
        out[OFF_OBJ + b2] = s / (float)Nn; }
    }
  }
}

extern "C" void kernel_launch(void* const* d_in, const int* in_sizes, int n_in,
                              void* d_out, int out_size, void* d_ws, size_t ws_size,
                              hipStream_t stream) {
  const float* E  = (const float*)d_in[0];
  const float* LW = (const float*)d_in[1];
  float* out = (float*)d_out;
  char*  ws  = (char*)d_ws;
  (void)in_sizes; (void)n_in; (void)out_size; (void)ws_size;
  kinit<<<dim3(1),    dim3(1024), 0, stream>>>(E, ws);
  kmain<<<dim3(NBLK), dim3(128),  0, stream>>>(E, LW, out, ws);
}